// Round 1
// baseline (1102.992 us; speedup 1.0000x reference)
//
#include <hip/hip_runtime.h>
#include <hip/hip_bf16.h>

typedef __attribute__((ext_vector_type(8))) short short8;
typedef __attribute__((ext_vector_type(8))) unsigned short ushort8;
typedef __attribute__((ext_vector_type(4))) float f32x4;

__device__ __forceinline__ unsigned short f2bf(float f) {
    union { float f; unsigned int u; } v; v.f = f;
    unsigned int r = v.u + 0x7FFFu + ((v.u >> 16) & 1u);
    return (unsigned short)(r >> 16);
}

// Transpose W1, W2 into bf16 [j][k] layout so MFMA B-frags are k-contiguous.
__global__ __launch_bounds__(256) void prep_w_kernel(
    const float* __restrict__ W1, const float* __restrict__ W2,
    unsigned short* __restrict__ wt1, unsigned short* __restrict__ wt2)
{
    int t = blockIdx.x * 256 + threadIdx.x;   // 0..16383
    int k = t >> 7, j = t & 127;
    wt1[j * 128 + k] = f2bf(W1[t]);
    wt2[j * 128 + k] = f2bf(W2[t]);
}

// One 32-lane group per edge; float4 per lane (128 floats per edge).
__global__ __launch_bounds__(256) void scatter_kernel(
    const float* __restrict__ x, const int* __restrict__ src,
    const int* __restrict__ dst, const float* __restrict__ ew,
    float* __restrict__ agg, int E)
{
    int t = blockIdx.x * 256 + threadIdx.x;
    int e = t >> 5;
    if (e >= E) return;
    int s = t & 31;
    int si = src[e], di = dst[e];
    float w = ew[e];
    float4 v = reinterpret_cast<const float4*>(x)[(size_t)si * 32 + s];
    float* o = agg + (size_t)di * 128 + (size_t)s * 4;
    unsafeAtomicAdd(o + 0, w * v.x);
    unsafeAtomicAdd(o + 1, w * v.y);
    unsafeAtomicAdd(o + 2, w * v.z);
    unsafeAtomicAdd(o + 3, w * v.w);
}

// out = x + agg (EPS=0), converted to bf16 for the MFMA MLP.
__global__ __launch_bounds__(256) void add_conv_kernel(
    const float* __restrict__ x, const float* __restrict__ agg,
    unsigned short* __restrict__ outb, int n8)
{
    int t = blockIdx.x * 256 + threadIdx.x;
    if (t >= n8) return;
    float4 x0 = reinterpret_cast<const float4*>(x)[t * 2];
    float4 x1 = reinterpret_cast<const float4*>(x)[t * 2 + 1];
    float4 a0 = reinterpret_cast<const float4*>(agg)[t * 2];
    float4 a1 = reinterpret_cast<const float4*>(agg)[t * 2 + 1];
    ushort8 o;
    o[0] = f2bf(x0.x + a0.x); o[1] = f2bf(x0.y + a0.y);
    o[2] = f2bf(x0.z + a0.z); o[3] = f2bf(x0.w + a0.w);
    o[4] = f2bf(x1.x + a1.x); o[5] = f2bf(x1.y + a1.y);
    o[6] = f2bf(x1.z + a1.z); o[7] = f2bf(x1.w + a1.w);
    reinterpret_cast<ushort8*>(outb)[t] = o;
}

// Fused MLP: y = relu(out @ W1 + b1) @ W2 + b2 via mfma_f32_16x16x32_bf16.
// Block = 256 thr (4 waves), 64 rows/block; each wave owns a 16-row strip.
#define LDH 136   // pad 128 -> 136 ushorts (272 B row, 16B-aligned, spreads banks)
__global__ __launch_bounds__(256) void mlp_kernel(
    const unsigned short* __restrict__ outb,
    const unsigned short* __restrict__ wt1,
    const unsigned short* __restrict__ wt2,
    const float* __restrict__ b1, const float* __restrict__ b2,
    float* __restrict__ y, int N)
{
    __shared__ __align__(16) unsigned short Hs[64][LDH];
    int tid  = threadIdx.x;
    int wave = tid >> 6;
    int lane = tid & 63;
    int r    = lane & 15;   // A-row / B-col / C-col
    int kg   = lane >> 4;   // k-octet group; C rows = kg*4+reg
    int row0 = blockIdx.x * 64 + wave * 16;

    // A-frags for GEMM1 straight from global bf16 (16B/lane, coalesced).
    short8 a[4];
    {
        int arow = row0 + r;
        if (arow >= N) arow = N - 1;   // tail clamp; stores are guarded
        const unsigned short* ab = outb + (size_t)arow * 128 + kg * 8;
        #pragma unroll
        for (int kt = 0; kt < 4; ++kt)
            a[kt] = *reinterpret_cast<const short8*>(ab + kt * 32);
    }

    f32x4 acc[8];
    #pragma unroll
    for (int jt = 0; jt < 8; ++jt) acc[jt] = {0.f, 0.f, 0.f, 0.f};

    #pragma unroll
    for (int jt = 0; jt < 8; ++jt) {
        const unsigned short* bb = wt1 + (jt * 16 + r) * 128 + kg * 8;
        #pragma unroll
        for (int kt = 0; kt < 4; ++kt) {
            short8 b = *reinterpret_cast<const short8*>(bb + kt * 32);
            acc[jt] = __builtin_amdgcn_mfma_f32_16x16x32_bf16(a[kt], b, acc[jt], 0, 0, 0);
        }
    }

    // bias + ReLU, park h (bf16) in LDS for the inter-GEMM transpose.
    #pragma unroll
    for (int jt = 0; jt < 8; ++jt) {
        float bias = b1[jt * 16 + r];
        #pragma unroll
        for (int reg = 0; reg < 4; ++reg) {
            float h = fmaxf(acc[jt][reg] + bias, 0.0f);
            Hs[wave * 16 + kg * 4 + reg][jt * 16 + r] = f2bf(h);
        }
    }
    __syncthreads();

    short8 a2[4];
    #pragma unroll
    for (int kt = 0; kt < 4; ++kt)
        a2[kt] = *reinterpret_cast<const short8*>(&Hs[wave * 16 + r][kt * 32 + kg * 8]);

    f32x4 acc2[8];
    #pragma unroll
    for (int jt = 0; jt < 8; ++jt) acc2[jt] = {0.f, 0.f, 0.f, 0.f};

    #pragma unroll
    for (int jt = 0; jt < 8; ++jt) {
        const unsigned short* bb = wt2 + (jt * 16 + r) * 128 + kg * 8;
        #pragma unroll
        for (int kt = 0; kt < 4; ++kt) {
            short8 b = *reinterpret_cast<const short8*>(bb + kt * 32);
            acc2[jt] = __builtin_amdgcn_mfma_f32_16x16x32_bf16(a2[kt], b, acc2[jt], 0, 0, 0);
        }
    }

    #pragma unroll
    for (int jt = 0; jt < 8; ++jt) {
        float bias = b2[jt * 16 + r];
        #pragma unroll
        for (int reg = 0; reg < 4; ++reg) {
            int orow = row0 + kg * 4 + reg;
            if (orow < N)
                y[(size_t)orow * 128 + jt * 16 + r] = acc2[jt][reg] + bias;
        }
    }
}

extern "C" void kernel_launch(void* const* d_in, const int* in_sizes, int n_in,
                              void* d_out, int out_size, void* d_ws, size_t ws_size,
                              hipStream_t stream) {
    const float* x  = (const float*)d_in[0];
    const int*   ei = (const int*)d_in[1];      // [2,E] as int32 per harness
    const float* ew = (const float*)d_in[2];
    const float* W1 = (const float*)d_in[3];
    const float* b1 = (const float*)d_in[4];
    const float* W2 = (const float*)d_in[5];
    const float* b2 = (const float*)d_in[6];
    float* y = (float*)d_out;

    const int N = in_sizes[0] / 128;   // 100000
    const int E = in_sizes[2];         // 600000
    const size_t ND = (size_t)N * 128;

    char* ws = (char*)d_ws;
    float*          agg  = (float*)ws;                       // ND f32
    unsigned short* outb = (unsigned short*)(ws + ND * 4);   // ND bf16
    unsigned short* wt1  = (unsigned short*)(ws + ND * 6);   // 128*128 bf16
    unsigned short* wt2  = wt1 + 128 * 128;

    hipMemsetAsync(agg, 0, ND * 4, stream);
    prep_w_kernel<<<64, 256, 0, stream>>>(W1, W2, wt1, wt2);
    scatter_kernel<<<(int)(((size_t)E * 32 + 255) / 256), 256, 0, stream>>>(
        x, ei, ei + E, ew, agg, E);
    add_conv_kernel<<<(int)((ND / 8 + 255) / 256), 256, 0, stream>>>(
        x, agg, outb, (int)(ND / 8));
    mlp_kernel<<<(N + 63) / 64, 256, 0, stream>>>(outb, wt1, wt2, b1, b2, y, N);
}

// Round 2
// 211.402 us; speedup vs baseline: 5.2175x; 5.2175x over previous
//
#include <hip/hip_runtime.h>
#include <hip/hip_bf16.h>

typedef __attribute__((ext_vector_type(8))) short short8;
typedef __attribute__((ext_vector_type(4))) unsigned short ushort4v;
typedef __attribute__((ext_vector_type(4))) float f32x4;

__device__ __forceinline__ unsigned short f2bf(float f) {
    union { float f; unsigned int u; } v; v.f = f;
    unsigned int r = v.u + 0x7FFFu + ((v.u >> 16) & 1u);
    return (unsigned short)(r >> 16);
}

// Transpose W1, W2 into bf16 [j][k] layout so MFMA B-frags are k-contiguous.
__global__ __launch_bounds__(256) void prep_w_kernel(
    const float* __restrict__ W1, const float* __restrict__ W2,
    unsigned short* __restrict__ wt1, unsigned short* __restrict__ wt2)
{
    int t = blockIdx.x * 256 + threadIdx.x;   // 0..16383
    int k = t >> 7, j = t & 127;
    wt1[j * 128 + k] = f2bf(W1[t]);
    wt2[j * 128 + k] = f2bf(W2[t]);
}

// ---- CSR build: histogram -> 3-phase exclusive scan -> scatter ----

__global__ __launch_bounds__(256) void hist_kernel(
    const int* __restrict__ dst, int* __restrict__ offs, int E)
{
    int e = blockIdx.x * 256 + threadIdx.x;
    if (e < E) atomicAdd(&offs[dst[e]], 1);
}

// Per-block exclusive scan over chunks of 1024 (256 thr x 4), in place.
__global__ __launch_bounds__(256) void scan1_kernel(
    int* __restrict__ offs, int* __restrict__ bsums, int N)
{
    __shared__ int tsum[256];
    int b = blockIdx.x, t = threadIdx.x;
    int base = b * 1024 + t * 4;
    int v[4]; int tl = 0;
    #pragma unroll
    for (int j = 0; j < 4; ++j) {
        v[j] = (base + j < N) ? offs[base + j] : 0;
        tl += v[j];
    }
    tsum[t] = tl; __syncthreads();
    for (int off = 1; off < 256; off <<= 1) {
        int u = (t >= off) ? tsum[t - off] : 0;
        __syncthreads();
        tsum[t] += u;
        __syncthreads();
    }
    int run = tsum[t] - tl;   // exclusive
    #pragma unroll
    for (int j = 0; j < 4; ++j) {
        if (base + j < N) offs[base + j] = run;
        run += v[j];
    }
    if (t == 255) bsums[b] = tsum[255];
}

__global__ void scan2_kernel(int* __restrict__ bsums, int* __restrict__ offs,
                             int nb, int N, int E)
{
    // single thread: exclusive scan of <=128 block sums
    int run = 0;
    for (int i = 0; i < nb; ++i) { int t = bsums[i]; bsums[i] = run; run += t; }
    offs[N] = E;
}

__global__ __launch_bounds__(256) void scan3_kernel(
    int* __restrict__ offs, const int* __restrict__ bsums,
    int* __restrict__ cursor, int N)
{
    int i = blockIdx.x * 256 + threadIdx.x;
    if (i < N) {
        int v = offs[i] + bsums[i >> 10];
        offs[i] = v;
        cursor[i] = v;
    }
}

__global__ __launch_bounds__(256) void scatter2_kernel(
    const int* __restrict__ src, const int* __restrict__ dst,
    const float* __restrict__ ew, int* __restrict__ cursor,
    int* __restrict__ srcs, float* __restrict__ wsrt, int E)
{
    int e = blockIdx.x * 256 + threadIdx.x;
    if (e >= E) return;
    int pos = atomicAdd(&cursor[dst[e]], 1);
    srcs[pos] = src[e];
    wsrt[pos] = ew[e];
}

// ---- Gather: one 32-lane group per node; acc in regs; write bf16 once ----
__global__ __launch_bounds__(256) void gather_kernel(
    const float* __restrict__ x, const int* __restrict__ offs,
    const int* __restrict__ srcs, const float* __restrict__ wsrt,
    unsigned short* __restrict__ outb, int N)
{
    int t = blockIdx.x * 256 + threadIdx.x;
    int node = t >> 5;
    if (node >= N) return;
    int lane = t & 31;
    const float4* xr = reinterpret_cast<const float4*>(x);
    float4 acc = xr[(size_t)node * 32 + lane];   // (1+EPS)*x self-term
    int s = offs[node], e = offs[node + 1];
    for (int i = s; i < e; ++i) {
        int sn = srcs[i];
        float w = wsrt[i];
        float4 v = xr[(size_t)sn * 32 + lane];
        acc.x += w * v.x; acc.y += w * v.y;
        acc.z += w * v.z; acc.w += w * v.w;
    }
    ushort4v o;
    o[0] = f2bf(acc.x); o[1] = f2bf(acc.y);
    o[2] = f2bf(acc.z); o[3] = f2bf(acc.w);
    reinterpret_cast<ushort4v*>(outb + (size_t)node * 128)[lane] = o;
}

// ---- Fused MLP: y = relu(out @ W1 + b1) @ W2 + b2 (mfma 16x16x32 bf16) ----
#define LDH 136
__global__ __launch_bounds__(256) void mlp_kernel(
    const unsigned short* __restrict__ outb,
    const unsigned short* __restrict__ wt1,
    const unsigned short* __restrict__ wt2,
    const float* __restrict__ b1, const float* __restrict__ b2,
    float* __restrict__ y, int N)
{
    __shared__ __align__(16) unsigned short Hs[64][LDH];
    int tid  = threadIdx.x;
    int wave = tid >> 6;
    int lane = tid & 63;
    int r    = lane & 15;
    int kg   = lane >> 4;
    int row0 = blockIdx.x * 64 + wave * 16;

    short8 a[4];
    {
        int arow = row0 + r;
        if (arow >= N) arow = N - 1;
        const unsigned short* ab = outb + (size_t)arow * 128 + kg * 8;
        #pragma unroll
        for (int kt = 0; kt < 4; ++kt)
            a[kt] = *reinterpret_cast<const short8*>(ab + kt * 32);
    }

    f32x4 acc[8];
    #pragma unroll
    for (int jt = 0; jt < 8; ++jt) acc[jt] = {0.f, 0.f, 0.f, 0.f};

    #pragma unroll
    for (int jt = 0; jt < 8; ++jt) {
        const unsigned short* bb = wt1 + (jt * 16 + r) * 128 + kg * 8;
        #pragma unroll
        for (int kt = 0; kt < 4; ++kt) {
            short8 b = *reinterpret_cast<const short8*>(bb + kt * 32);
            acc[jt] = __builtin_amdgcn_mfma_f32_16x16x32_bf16(a[kt], b, acc[jt], 0, 0, 0);
        }
    }

    #pragma unroll
    for (int jt = 0; jt < 8; ++jt) {
        float bias = b1[jt * 16 + r];
        #pragma unroll
        for (int reg = 0; reg < 4; ++reg) {
            float h = fmaxf(acc[jt][reg] + bias, 0.0f);
            Hs[wave * 16 + kg * 4 + reg][jt * 16 + r] = f2bf(h);
        }
    }
    __syncthreads();

    short8 a2[4];
    #pragma unroll
    for (int kt = 0; kt < 4; ++kt)
        a2[kt] = *reinterpret_cast<const short8*>(&Hs[wave * 16 + r][kt * 32 + kg * 8]);

    f32x4 acc2[8];
    #pragma unroll
    for (int jt = 0; jt < 8; ++jt) acc2[jt] = {0.f, 0.f, 0.f, 0.f};

    #pragma unroll
    for (int jt = 0; jt < 8; ++jt) {
        const unsigned short* bb = wt2 + (jt * 16 + r) * 128 + kg * 8;
        #pragma unroll
        for (int kt = 0; kt < 4; ++kt) {
            short8 b = *reinterpret_cast<const short8*>(bb + kt * 32);
            acc2[jt] = __builtin_amdgcn_mfma_f32_16x16x32_bf16(a2[kt], b, acc2[jt], 0, 0, 0);
        }
    }

    #pragma unroll
    for (int jt = 0; jt < 8; ++jt) {
        float bias = b2[jt * 16 + r];
        #pragma unroll
        for (int reg = 0; reg < 4; ++reg) {
            int orow = row0 + kg * 4 + reg;
            if (orow < N)
                y[(size_t)orow * 128 + jt * 16 + r] = acc2[jt][reg] + bias;
        }
    }
}

extern "C" void kernel_launch(void* const* d_in, const int* in_sizes, int n_in,
                              void* d_out, int out_size, void* d_ws, size_t ws_size,
                              hipStream_t stream) {
    const float* x  = (const float*)d_in[0];
    const int*   ei = (const int*)d_in[1];      // [2,E] as int32
    const float* ew = (const float*)d_in[2];
    const float* W1 = (const float*)d_in[3];
    const float* b1 = (const float*)d_in[4];
    const float* W2 = (const float*)d_in[5];
    const float* b2 = (const float*)d_in[6];
    float* y = (float*)d_out;

    const int N = in_sizes[0] / 128;   // 100000
    const int E = in_sizes[2];         // 600000
    const size_t ND = (size_t)N * 128;
    const int nb = (N + 1023) / 1024;  // scan chunks

    // workspace layout (256B aligned bumps)
    char* ws = (char*)d_ws;
    size_t off = 0;
    auto bump = [&](size_t bytes) {
        void* p = ws + off;
        off += (bytes + 255) & ~(size_t)255;
        return p;
    };
    unsigned short* outb   = (unsigned short*)bump(ND * 2);          // 25.6 MB
    unsigned short* wt1    = (unsigned short*)bump(128 * 128 * 2);
    unsigned short* wt2    = (unsigned short*)bump(128 * 128 * 2);
    int*            offs   = (int*)bump((size_t)(N + 1) * 4);
    int*            cursor = (int*)bump((size_t)N * 4);
    int*            bsums  = (int*)bump(1024);
    int*            srcs   = (int*)bump((size_t)E * 4);
    float*          wsrt   = (float*)bump((size_t)E * 4);

    const int* src = ei;
    const int* dst = ei + E;

    hipMemsetAsync(offs, 0, (size_t)N * 4, stream);
    prep_w_kernel<<<64, 256, 0, stream>>>(W1, W2, wt1, wt2);
    hist_kernel<<<(E + 255) / 256, 256, 0, stream>>>(dst, offs, E);
    scan1_kernel<<<nb, 256, 0, stream>>>(offs, bsums, N);
    scan2_kernel<<<1, 1, 0, stream>>>(bsums, offs, nb, N, E);
    scan3_kernel<<<(N + 255) / 256, 256, 0, stream>>>(offs, bsums, cursor, N);
    scatter2_kernel<<<(E + 255) / 256, 256, 0, stream>>>(src, dst, ew, cursor,
                                                         srcs, wsrt, E);
    gather_kernel<<<(N * 32 + 255) / 256, 256, 0, stream>>>(x, offs, srcs, wsrt,
                                                            outb, N);
    mlp_kernel<<<(N + 63) / 64, 256, 0, stream>>>(outb, wt1, wt2, b1, b2, y, N);
}

// Round 3
// 187.702 us; speedup vs baseline: 5.8763x; 1.1263x over previous
//
#include <hip/hip_runtime.h>
#include <hip/hip_bf16.h>

typedef __attribute__((ext_vector_type(8))) short short8;
typedef __attribute__((ext_vector_type(4))) unsigned short ushort4v;
typedef __attribute__((ext_vector_type(4))) float f32x4;

__device__ __forceinline__ unsigned short f2bf(float f) {
    union { float f; unsigned int u; } v; v.f = f;
    unsigned int r = v.u + 0x7FFFu + ((v.u >> 16) & 1u);
    return (unsigned short)(r >> 16);
}

// Pre-permute W1,W2 into MFMA-fragment-linear bf16 layout:
// frag tile (jt,kt) for lane (kg*16+r), elem e  <-  W[k = kt*32+kg*8+e][j = jt*16+r]
// address = (jt*4+kt)*512 + lane*8 + e   -> B-loads in the MLP are fully coalesced.
__global__ __launch_bounds__(256) void prep_w_kernel(
    const float* __restrict__ W1, const float* __restrict__ W2,
    unsigned short* __restrict__ wtf1, unsigned short* __restrict__ wtf2)
{
    int t = blockIdx.x * 256 + threadIdx.x;   // 0..16383
    int k = t >> 7, j = t & 127;
    int jt = j >> 4, r = j & 15, kt = k >> 5, kg = (k >> 3) & 3, e = k & 7;
    int flin = (jt * 4 + kt) * 512 + (kg * 16 + r) * 8 + e;
    wtf1[flin] = f2bf(W1[t]);
    wtf2[flin] = f2bf(W2[t]);
}

// ---- CSR build ----

__global__ __launch_bounds__(256) void hist_kernel(
    const int* __restrict__ dst, int* __restrict__ offs, int E)
{
    int e = blockIdx.x * 256 + threadIdx.x;
    if (e < E) atomicAdd(&offs[dst[e]], 1);
}

__global__ __launch_bounds__(256) void scan1_kernel(
    int* __restrict__ offs, int* __restrict__ bsums, int N)
{
    __shared__ int tsum[256];
    int b = blockIdx.x, t = threadIdx.x;
    int base = b * 1024 + t * 4;
    int v[4]; int tl = 0;
    #pragma unroll
    for (int j = 0; j < 4; ++j) {
        v[j] = (base + j < N) ? offs[base + j] : 0;
        tl += v[j];
    }
    tsum[t] = tl; __syncthreads();
    for (int off = 1; off < 256; off <<= 1) {
        int u = (t >= off) ? tsum[t - off] : 0;
        __syncthreads();
        tsum[t] += u;
        __syncthreads();
    }
    int run = tsum[t] - tl;   // exclusive
    #pragma unroll
    for (int j = 0; j < 4; ++j) {
        if (base + j < N) offs[base + j] = run;
        run += v[j];
    }
    if (t == 255) bsums[b] = tsum[255];
}

// Parallel block-sum scan (nb <= 128 for N <= 131072) — replaces serial 1-thread scan.
__global__ __launch_bounds__(128) void scan2_kernel(
    int* __restrict__ bsums, int* __restrict__ offs, int nb, int N, int E)
{
    __shared__ int s[128];
    int t = threadIdx.x;
    int v = (t < nb) ? bsums[t] : 0;
    s[t] = v; __syncthreads();
    for (int off = 1; off < 128; off <<= 1) {
        int u = (t >= off) ? s[t - off] : 0;
        __syncthreads();
        s[t] += u;
        __syncthreads();
    }
    if (t < nb) bsums[t] = s[t] - v;   // exclusive
    if (t == 0) offs[N] = E;
}

__global__ __launch_bounds__(256) void scan3_kernel(
    int* __restrict__ offs, const int* __restrict__ bsums,
    int* __restrict__ cursor, int N)
{
    int i = blockIdx.x * 256 + threadIdx.x;
    if (i < N) {
        int v = offs[i] + bsums[i >> 10];
        offs[i] = v;
        cursor[i] = v;
    }
}

__global__ __launch_bounds__(256) void scatter2_kernel(
    const int* __restrict__ src, const int* __restrict__ dst,
    const float* __restrict__ ew, int* __restrict__ cursor,
    int* __restrict__ srcs, float* __restrict__ wsrt, int E)
{
    int e = blockIdx.x * 256 + threadIdx.x;
    if (e >= E) return;
    int pos = atomicAdd(&cursor[dst[e]], 1);
    srcs[pos] = src[e];
    wsrt[pos] = ew[e];
}

// ---- Fused: CSR gather -> bf16 LDS tile -> 2x MFMA GEMM -> y ----
// 64 nodes/block, 256 threads. LDS tile Hs[64][128] bf16, XOR-chunk swizzle:
// element (m, k) lives at short-offset m*128 + ((k>>3) ^ (m&7))*8 + (k&7).
// This balances the 16-row fragment reads across all 32 banks.
__global__ __launch_bounds__(256) void fused_kernel(
    const float* __restrict__ x, const int* __restrict__ offs,
    const int* __restrict__ srcs, const float* __restrict__ wsrt,
    const unsigned short* __restrict__ wtf1,
    const unsigned short* __restrict__ wtf2,
    const float* __restrict__ b1, const float* __restrict__ b2,
    float* __restrict__ y, int N)
{
    __shared__ __align__(16) unsigned short Hs[64 * 128];
    int tid = threadIdx.x;
    int node0 = blockIdx.x * 64;

    // Phase 1: gather. 8 groups x 32 lanes; group g does rows {g, g+8, ...}.
    {
        int g = tid >> 5, l = tid & 31;
        const float4* xr = reinterpret_cast<const float4*>(x);
        for (int it = 0; it < 8; ++it) {
            int m = it * 8 + g;
            int node = node0 + m;
            float4 acc = {0.f, 0.f, 0.f, 0.f};
            if (node < N) {
                acc = xr[(size_t)node * 32 + l];          // self-term (EPS=0)
                int s = offs[node], e = offs[node + 1];
                for (int i = s; i < e; ++i) {
                    int sn = srcs[i];
                    float w = wsrt[i];
                    float4 v = xr[(size_t)sn * 32 + l];
                    acc.x += w * v.x; acc.y += w * v.y;
                    acc.z += w * v.z; acc.w += w * v.w;
                }
            }
            ushort4v o;
            o[0] = f2bf(acc.x); o[1] = f2bf(acc.y);
            o[2] = f2bf(acc.z); o[3] = f2bf(acc.w);
            // k = 4l..4l+3 -> chunk l>>1, half l&1
            int soff = m * 128 + (((l >> 1) ^ (m & 7)) << 3) + ((l & 1) << 2);
            *reinterpret_cast<ushort4v*>(&Hs[soff]) = o;
        }
    }
    __syncthreads();

    int wave = tid >> 6, lane = tid & 63;
    int r = lane & 15, kg = lane >> 4;
    int row0 = node0 + wave * 16;
    int mr = wave * 16 + r;

    // A-frags from swizzled LDS
    short8 a[4];
    #pragma unroll
    for (int kt = 0; kt < 4; ++kt)
        a[kt] = *reinterpret_cast<const short8*>(
            &Hs[mr * 128 + (((kt * 4 + kg) ^ (r & 7)) << 3)]);

    f32x4 acc1[8];
    #pragma unroll
    for (int jt = 0; jt < 8; ++jt) acc1[jt] = {0.f, 0.f, 0.f, 0.f};

    #pragma unroll
    for (int jt = 0; jt < 8; ++jt) {
        #pragma unroll
        for (int kt = 0; kt < 4; ++kt) {
            short8 b = *reinterpret_cast<const short8*>(
                wtf1 + ((jt * 4 + kt) << 9) + (lane << 3));   // coalesced
            acc1[jt] = __builtin_amdgcn_mfma_f32_16x16x32_bf16(a[kt], b, acc1[jt], 0, 0, 0);
        }
    }

    // bias + ReLU -> h back into the (wave-private rows of the) same LDS tile
    #pragma unroll
    for (int jt = 0; jt < 8; ++jt) {
        float bias = b1[jt * 16 + r];
        int col = jt * 16 + r;
        #pragma unroll
        for (int reg = 0; reg < 4; ++reg) {
            int m2 = wave * 16 + kg * 4 + reg;
            float h = fmaxf(acc1[jt][reg] + bias, 0.0f);
            Hs[m2 * 128 + (((col >> 3) ^ (m2 & 7)) << 3) + (col & 7)] = f2bf(h);
        }
    }
    __syncthreads();

    short8 a2[4];
    #pragma unroll
    for (int kt = 0; kt < 4; ++kt)
        a2[kt] = *reinterpret_cast<const short8*>(
            &Hs[mr * 128 + (((kt * 4 + kg) ^ (r & 7)) << 3)]);

    f32x4 acc2[8];
    #pragma unroll
    for (int jt = 0; jt < 8; ++jt) acc2[jt] = {0.f, 0.f, 0.f, 0.f};

    #pragma unroll
    for (int jt = 0; jt < 8; ++jt) {
        #pragma unroll
        for (int kt = 0; kt < 4; ++kt) {
            short8 b = *reinterpret_cast<const short8*>(
                wtf2 + ((jt * 4 + kt) << 9) + (lane << 3));
            acc2[jt] = __builtin_amdgcn_mfma_f32_16x16x32_bf16(a2[kt], b, acc2[jt], 0, 0, 0);
        }
    }

    #pragma unroll
    for (int jt = 0; jt < 8; ++jt) {
        float bias = b2[jt * 16 + r];
        #pragma unroll
        for (int reg = 0; reg < 4; ++reg) {
            int orow = row0 + kg * 4 + reg;
            if (orow < N)
                y[(size_t)orow * 128 + jt * 16 + r] = acc2[jt][reg] + bias;
        }
    }
}

extern "C" void kernel_launch(void* const* d_in, const int* in_sizes, int n_in,
                              void* d_out, int out_size, void* d_ws, size_t ws_size,
                              hipStream_t stream) {
    const float* x  = (const float*)d_in[0];
    const int*   ei = (const int*)d_in[1];      // [2,E] as int32
    const float* ew = (const float*)d_in[2];
    const float* W1 = (const float*)d_in[3];
    const float* b1 = (const float*)d_in[4];
    const float* W2 = (const float*)d_in[5];
    const float* b2 = (const float*)d_in[6];
    float* y = (float*)d_out;

    const int N = in_sizes[0] / 128;   // 100000
    const int E = in_sizes[2];         // 600000
    const int nb = (N + 1023) / 1024;  // scan chunks (98)

    char* ws = (char*)d_ws;
    size_t off = 0;
    auto bump = [&](size_t bytes) {
        void* p = ws + off;
        off += (bytes + 255) & ~(size_t)255;
        return p;
    };
    unsigned short* wtf1   = (unsigned short*)bump(128 * 128 * 2);
    unsigned short* wtf2   = (unsigned short*)bump(128 * 128 * 2);
    int*            offs   = (int*)bump((size_t)(N + 1) * 4);
    int*            cursor = (int*)bump((size_t)N * 4);
    int*            bsums  = (int*)bump(1024);
    int*            srcs   = (int*)bump((size_t)E * 4);
    float*          wsrt   = (float*)bump((size_t)E * 4);

    const int* src = ei;
    const int* dst = ei + E;

    hipMemsetAsync(offs, 0, (size_t)N * 4, stream);
    prep_w_kernel<<<64, 256, 0, stream>>>(W1, W2, wtf1, wtf2);
    hist_kernel<<<(E + 255) / 256, 256, 0, stream>>>(dst, offs, E);
    scan1_kernel<<<nb, 256, 0, stream>>>(offs, bsums, N);
    scan2_kernel<<<1, 128, 0, stream>>>(bsums, offs, nb, N, E);
    scan3_kernel<<<(N + 255) / 256, 256, 0, stream>>>(offs, bsums, cursor, N);
    scatter2_kernel<<<(E + 255) / 256, 256, 0, stream>>>(src, dst, ew, cursor,
                                                         srcs, wsrt, E);
    fused_kernel<<<(N + 63) / 64, 256, 0, stream>>>(x, offs, srcs, wsrt,
                                                    wtf1, wtf2, b1, b2, y, N);
}

// Round 4
// 158.518 us; speedup vs baseline: 6.9581x; 1.1841x over previous
//
#include <hip/hip_runtime.h>
#include <hip/hip_bf16.h>

typedef __attribute__((ext_vector_type(8))) short short8;
typedef __attribute__((ext_vector_type(4))) unsigned short ushort4v;
typedef __attribute__((ext_vector_type(4))) float f32x4;

__device__ __forceinline__ unsigned short f2bf(float f) {
    union { float f; unsigned int u; } v; v.f = f;
    unsigned int r = v.u + 0x7FFFu + ((v.u >> 16) & 1u);
    return (unsigned short)(r >> 16);
}

// Pre-permute W1,W2 into MFMA-fragment-linear bf16 layout:
// frag tile (jt,kt) for lane (kg*16+r), elem e  <-  W[k = kt*32+kg*8+e][j = jt*16+r]
__global__ __launch_bounds__(256) void prep_w_kernel(
    const float* __restrict__ W1, const float* __restrict__ W2,
    unsigned short* __restrict__ wtf1, unsigned short* __restrict__ wtf2)
{
    int t = blockIdx.x * 256 + threadIdx.x;   // 0..16383
    int k = t >> 7, j = t & 127;
    int jt = j >> 4, r = j & 15, kt = k >> 5, kg = (k >> 3) & 3, e = k & 7;
    int flin = (jt * 4 + kt) * 512 + (kg * 16 + r) * 8 + e;
    wtf1[flin] = f2bf(W1[t]);
    wtf2[flin] = f2bf(W2[t]);
}

// ---- CSR build ----

__global__ __launch_bounds__(256) void hist_kernel(
    const int* __restrict__ dst, int* __restrict__ offs, int E)
{
    int e = blockIdx.x * 256 + threadIdx.x;
    if (e < E) atomicAdd(&offs[dst[e]], 1);
}

__global__ __launch_bounds__(256) void scan1_kernel(
    int* __restrict__ offs, int* __restrict__ bsums, int N)
{
    __shared__ int tsum[256];
    int b = blockIdx.x, t = threadIdx.x;
    int base = b * 1024 + t * 4;
    int v[4]; int tl = 0;
    #pragma unroll
    for (int j = 0; j < 4; ++j) {
        v[j] = (base + j < N) ? offs[base + j] : 0;
        tl += v[j];
    }
    tsum[t] = tl; __syncthreads();
    for (int off = 1; off < 256; off <<= 1) {
        int u = (t >= off) ? tsum[t - off] : 0;
        __syncthreads();
        tsum[t] += u;
        __syncthreads();
    }
    int run = tsum[t] - tl;   // exclusive
    #pragma unroll
    for (int j = 0; j < 4; ++j) {
        if (base + j < N) offs[base + j] = run;
        run += v[j];
    }
    if (t == 255) bsums[b] = tsum[255];
}

__global__ __launch_bounds__(128) void scan2_kernel(
    int* __restrict__ bsums, int* __restrict__ offs, int nb, int N, int E)
{
    __shared__ int s[128];
    int t = threadIdx.x;
    int v = (t < nb) ? bsums[t] : 0;
    s[t] = v; __syncthreads();
    for (int off = 1; off < 128; off <<= 1) {
        int u = (t >= off) ? s[t - off] : 0;
        __syncthreads();
        s[t] += u;
        __syncthreads();
    }
    if (t < nb) bsums[t] = s[t] - v;   // exclusive
    if (t == 0) offs[N] = E;
}

__global__ __launch_bounds__(256) void scan3_kernel(
    int* __restrict__ offs, const int* __restrict__ bsums,
    int* __restrict__ cursor, int N)
{
    int i = blockIdx.x * 256 + threadIdx.x;
    if (i < N) {
        int v = offs[i] + bsums[i >> 10];
        offs[i] = v;
        cursor[i] = v;
    }
}

__global__ __launch_bounds__(256) void scatter2_kernel(
    const int* __restrict__ src, const int* __restrict__ dst,
    const float* __restrict__ ew, int* __restrict__ cursor,
    int* __restrict__ srcs, float* __restrict__ wsrt, int E)
{
    int e = blockIdx.x * 256 + threadIdx.x;
    if (e >= E) return;
    int pos = atomicAdd(&cursor[dst[e]], 1);
    srcs[pos] = src[e];
    wsrt[pos] = ew[e];
}

// ---- Fused: CSR gather (MLP-deep) -> bf16 LDS tile -> 2x MFMA GEMM -> y ----
__global__ __launch_bounds__(256) void fused_kernel(
    const float* __restrict__ x, const int* __restrict__ offs,
    const int* __restrict__ srcs, const float* __restrict__ wsrt,
    const unsigned short* __restrict__ wtf1,
    const unsigned short* __restrict__ wtf2,
    const float* __restrict__ b1, const float* __restrict__ b2,
    float* __restrict__ y, int N)
{
    __shared__ __align__(16) unsigned short Hs[64 * 128];
    int tid = threadIdx.x;
    int node0 = blockIdx.x * 64;

    // Phase 1: gather. 8 groups x 32 lanes; group g does rows {g, g+8, ...}.
    // Edge metadata coop-loaded (1 coalesced load / 32 edges), broadcast by
    // shuffle; gathers issued 4-at-a-time so 4 misses are in flight.
    {
        int g = tid >> 5, l = tid & 31;
        const float4* xr = reinterpret_cast<const float4*>(x);
        for (int it = 0; it < 8; ++it) {
            int m = it * 8 + g;
            int node = node0 + m;
            float4 acc = {0.f, 0.f, 0.f, 0.f};
            if (node < N) {
                acc = xr[(size_t)node * 32 + l];          // self-term (EPS=0)
                int s = offs[node], e = offs[node + 1];
                for (int base = s; base < e; base += 32) {
                    int cnt = min(e - base, 32);
                    int sv = 0; float wv = 0.f;            // idle slots: row 0, w=0
                    if (l < cnt) { sv = srcs[base + l]; wv = wsrt[base + l]; }
                    for (int j = 0; j < cnt; j += 4) {
                        int   s0 = __shfl(sv, j,     32);
                        int   s1 = __shfl(sv, j + 1, 32);
                        int   s2 = __shfl(sv, j + 2, 32);
                        int   s3 = __shfl(sv, j + 3, 32);
                        float w0 = __shfl(wv, j,     32);
                        float w1 = __shfl(wv, j + 1, 32);
                        float w2 = __shfl(wv, j + 2, 32);
                        float w3 = __shfl(wv, j + 3, 32);
                        float4 v0 = xr[(size_t)s0 * 32 + l];
                        float4 v1 = xr[(size_t)s1 * 32 + l];
                        float4 v2 = xr[(size_t)s2 * 32 + l];
                        float4 v3 = xr[(size_t)s3 * 32 + l];
                        acc.x += w0 * v0.x; acc.y += w0 * v0.y;
                        acc.z += w0 * v0.z; acc.w += w0 * v0.w;
                        acc.x += w1 * v1.x; acc.y += w1 * v1.y;
                        acc.z += w1 * v1.z; acc.w += w1 * v1.w;
                        acc.x += w2 * v2.x; acc.y += w2 * v2.y;
                        acc.z += w2 * v2.z; acc.w += w2 * v2.w;
                        acc.x += w3 * v3.x; acc.y += w3 * v3.y;
                        acc.z += w3 * v3.z; acc.w += w3 * v3.w;
                    }
                }
            }
            ushort4v o;
            o[0] = f2bf(acc.x); o[1] = f2bf(acc.y);
            o[2] = f2bf(acc.z); o[3] = f2bf(acc.w);
            int soff = m * 128 + (((l >> 1) ^ (m & 7)) << 3) + ((l & 1) << 2);
            *reinterpret_cast<ushort4v*>(&Hs[soff]) = o;
        }
    }
    __syncthreads();

    int wave = tid >> 6, lane = tid & 63;
    int r = lane & 15, kg = lane >> 4;
    int row0 = node0 + wave * 16;
    int mr = wave * 16 + r;

    short8 a[4];
    #pragma unroll
    for (int kt = 0; kt < 4; ++kt)
        a[kt] = *reinterpret_cast<const short8*>(
            &Hs[mr * 128 + (((kt * 4 + kg) ^ (r & 7)) << 3)]);

    f32x4 acc1[8];
    #pragma unroll
    for (int jt = 0; jt < 8; ++jt) acc1[jt] = {0.f, 0.f, 0.f, 0.f};

    #pragma unroll
    for (int jt = 0; jt < 8; ++jt) {
        #pragma unroll
        for (int kt = 0; kt < 4; ++kt) {
            short8 b = *reinterpret_cast<const short8*>(
                wtf1 + ((jt * 4 + kt) << 9) + (lane << 3));   // coalesced
            acc1[jt] = __builtin_amdgcn_mfma_f32_16x16x32_bf16(a[kt], b, acc1[jt], 0, 0, 0);
        }
    }

    #pragma unroll
    for (int jt = 0; jt < 8; ++jt) {
        float bias = b1[jt * 16 + r];
        int col = jt * 16 + r;
        #pragma unroll
        for (int reg = 0; reg < 4; ++reg) {
            int m2 = wave * 16 + kg * 4 + reg;
            float h = fmaxf(acc1[jt][reg] + bias, 0.0f);
            Hs[m2 * 128 + (((col >> 3) ^ (m2 & 7)) << 3) + (col & 7)] = f2bf(h);
        }
    }
    __syncthreads();

    short8 a2[4];
    #pragma unroll
    for (int kt = 0; kt < 4; ++kt)
        a2[kt] = *reinterpret_cast<const short8*>(
            &Hs[mr * 128 + (((kt * 4 + kg) ^ (r & 7)) << 3)]);

    f32x4 acc2[8];
    #pragma unroll
    for (int jt = 0; jt < 8; ++jt) acc2[jt] = {0.f, 0.f, 0.f, 0.f};

    #pragma unroll
    for (int jt = 0; jt < 8; ++jt) {
        #pragma unroll
        for (int kt = 0; kt < 4; ++kt) {
            short8 b = *reinterpret_cast<const short8*>(
                wtf2 + ((jt * 4 + kt) << 9) + (lane << 3));
            acc2[jt] = __builtin_amdgcn_mfma_f32_16x16x32_bf16(a2[kt], b, acc2[jt], 0, 0, 0);
        }
    }

    #pragma unroll
    for (int jt = 0; jt < 8; ++jt) {
        float bias = b2[jt * 16 + r];
        #pragma unroll
        for (int reg = 0; reg < 4; ++reg) {
            int orow = row0 + kg * 4 + reg;
            if (orow < N)
                y[(size_t)orow * 128 + jt * 16 + r] = acc2[jt][reg] + bias;
        }
    }
}

extern "C" void kernel_launch(void* const* d_in, const int* in_sizes, int n_in,
                              void* d_out, int out_size, void* d_ws, size_t ws_size,
                              hipStream_t stream) {
    const float* x  = (const float*)d_in[0];
    const int*   ei = (const int*)d_in[1];      // [2,E] as int32
    const float* ew = (const float*)d_in[2];
    const float* W1 = (const float*)d_in[3];
    const float* b1 = (const float*)d_in[4];
    const float* W2 = (const float*)d_in[5];
    const float* b2 = (const float*)d_in[6];
    float* y = (float*)d_out;

    const int N = in_sizes[0] / 128;   // 100000
    const int E = in_sizes[2];         // 600000
    const int nb = (N + 1023) / 1024;  // scan chunks (98)

    char* ws = (char*)d_ws;
    size_t off = 0;
    auto bump = [&](size_t bytes) {
        void* p = ws + off;
        off += (bytes + 255) & ~(size_t)255;
        return p;
    };
    unsigned short* wtf1   = (unsigned short*)bump(128 * 128 * 2);
    unsigned short* wtf2   = (unsigned short*)bump(128 * 128 * 2);
    int*            offs   = (int*)bump((size_t)(N + 1) * 4);
    int*            cursor = (int*)bump((size_t)N * 4);
    int*            bsums  = (int*)bump(1024);
    int*            srcs   = (int*)bump((size_t)E * 4);
    float*          wsrt   = (float*)bump((size_t)E * 4);

    const int* src = ei;
    const int* dst = ei + E;

    hipMemsetAsync(offs, 0, (size_t)N * 4, stream);
    prep_w_kernel<<<64, 256, 0, stream>>>(W1, W2, wtf1, wtf2);
    hist_kernel<<<(E + 255) / 256, 256, 0, stream>>>(dst, offs, E);
    scan1_kernel<<<nb, 256, 0, stream>>>(offs, bsums, N);
    scan2_kernel<<<1, 128, 0, stream>>>(bsums, offs, nb, N, E);
    scan3_kernel<<<(N + 255) / 256, 256, 0, stream>>>(offs, bsums, cursor, N);
    scatter2_kernel<<<(E + 255) / 256, 256, 0, stream>>>(src, dst, ew, cursor,
                                                         srcs, wsrt, E);
    fused_kernel<<<(N + 63) / 64, 256, 0, stream>>>(x, offs, srcs, wsrt,
                                                    wtf1, wtf2, b1, b2, y, N);
}